// Round 16
// baseline (366.643 us; speedup 1.0000x reference)
//
#include <hip/hip_runtime.h>
#include <cstdint>

// ---------------------------------------------------------------------------
// q[256][262144], s[512][262144] fp32.
// rank by d2 ~ s2[n] - 2*(q.s)[m][n]; per-row top-10 -> threshold -> row mask
// out = q * mask[row]
// K1: 256x256-tile split-K GEMM. R16: B staged via global_load_lds as RAW
//     fp32 (pre-swizzled source, linear dest; split at consume), A reg-staged
//     bf16 hi/lo (split once). Frees 16 VGPR -> 2-deep A-read ladder (3
//     rotating pairs). One barrier/step; counted lgkm+vmcnt; setprio on MFMA.
// K2: reduce partials + per-row top-10; K3: threshold+mask; K4: masked copy
// ---------------------------------------------------------------------------

typedef __attribute__((ext_vector_type(8))) __bf16 bf16x8;
typedef __attribute__((ext_vector_type(4))) float f32x4;
typedef __attribute__((ext_vector_type(4))) unsigned int uintx4;

#define KTOT 262144
#define MQ 256
#define NS 512
#define KSPLIT 128
#define KC 2048                 // KTOT / KSPLIT
#define BK 32
#define NSTEPS 64               // KC / BK
#define BBASE 32768             // B region offset inside a buffer
#define BUFB 65536              // one buffer: A(bf16 hi+lo) 32K + B(fp32) 32K

__device__ inline void gld16(const float* g, void* l) {
    __builtin_amdgcn_global_load_lds(
        (const __attribute__((address_space(1))) void*)g,
        (__attribute__((address_space(3))) void*)l,
        16, 0, 0);
}

__device__ inline unsigned int cvtpk_bf16(float a, float b) {
    unsigned int r;
    asm("v_cvt_pk_bf16_f32 %0, %1, %2" : "=v"(r) : "v"(a), "v"(b));
    return r; // r[15:0]=bf16(a), r[31:16]=bf16(b)
}

__device__ inline void split2(float a, float b, unsigned int& h, unsigned int& l) {
    h = cvtpk_bf16(a, b);
    float ra = a - __uint_as_float(h << 16);          // exact (Sterbenz)
    float rb = b - __uint_as_float(h & 0xFFFF0000u);  // exact
    l = cvtpk_bf16(ra, rb);
}

__device__ inline void split8u(const float4& x, const float4& y, uintx4& h, uintx4& l) {
    unsigned int h0, h1, h2, h3, l0, l1, l2, l3;
    split2(x.x, x.y, h0, l0);
    split2(x.z, x.w, h1, l1);
    split2(y.x, y.y, h2, l2);
    split2(y.z, y.w, h3, l3);
    h = (uintx4){h0, h1, h2, h3};
    l = (uintx4){l0, l1, l2, l3};
}

// fp32 pair -> bf16x8 hi/lo (for B at consume)
__device__ inline void split8v(const float4& x, const float4& y, bf16x8& hv, bf16x8& lv) {
    uintx4 h, l;
    split8u(x, y, h, l);
    hv = __builtin_bit_cast(bf16x8, h);
    lv = __builtin_bit_cast(bf16x8, l);
}

#define LDF(OFF) (*(const bf16x8*)&Lds[(OFF)])
#define SB __builtin_amdgcn_sched_barrier(0);
#define WAITL(N) asm volatile("s_waitcnt lgkmcnt(" #N ")" ::: "memory");

// term-major: 4 independent accumulator chains, dependent pairs 4 apart
#define MMB(MI, AH, AL)                                                                     \
    __builtin_amdgcn_s_setprio(1);                                                          \
    acc[MI][0] = __builtin_amdgcn_mfma_f32_16x16x32_bf16(AH, bh0, acc[MI][0], 0, 0, 0);     \
    acc[MI][1] = __builtin_amdgcn_mfma_f32_16x16x32_bf16(AH, bh1, acc[MI][1], 0, 0, 0);     \
    acc[MI][2] = __builtin_amdgcn_mfma_f32_16x16x32_bf16(AH, bh2, acc[MI][2], 0, 0, 0);     \
    acc[MI][3] = __builtin_amdgcn_mfma_f32_16x16x32_bf16(AH, bh3, acc[MI][3], 0, 0, 0);     \
    acc[MI][0] = __builtin_amdgcn_mfma_f32_16x16x32_bf16(AH, bl0, acc[MI][0], 0, 0, 0);     \
    acc[MI][1] = __builtin_amdgcn_mfma_f32_16x16x32_bf16(AH, bl1, acc[MI][1], 0, 0, 0);     \
    acc[MI][2] = __builtin_amdgcn_mfma_f32_16x16x32_bf16(AH, bl2, acc[MI][2], 0, 0, 0);     \
    acc[MI][3] = __builtin_amdgcn_mfma_f32_16x16x32_bf16(AH, bl3, acc[MI][3], 0, 0, 0);     \
    acc[MI][0] = __builtin_amdgcn_mfma_f32_16x16x32_bf16(AL, bh0, acc[MI][0], 0, 0, 0);     \
    acc[MI][1] = __builtin_amdgcn_mfma_f32_16x16x32_bf16(AL, bh1, acc[MI][1], 0, 0, 0);     \
    acc[MI][2] = __builtin_amdgcn_mfma_f32_16x16x32_bf16(AL, bh2, acc[MI][2], 0, 0, 0);     \
    acc[MI][3] = __builtin_amdgcn_mfma_f32_16x16x32_bf16(AL, bh3, acc[MI][3], 0, 0, 0);     \
    __builtin_amdgcn_s_setprio(0);

// ---------------------------------------------------------------------------
// K1: grid = 256 = 128 chunks x 2 ntiles, XCD-swizzled. block = 512 threads
// (8 waves, 2x4, wave 128x64).
// ---------------------------------------------------------------------------
__global__ __launch_bounds__(512, 2)
void k1_gemm(const float* __restrict__ Q, const float* __restrict__ S,
             float* __restrict__ Ppart, float* __restrict__ s2part)
{
    __shared__ __align__(16) unsigned char Lds[2 * BUFB];   // 128 KiB dbuf

    const int tid  = threadIdx.x;
    const int lane = tid & 63;
    const int w    = tid >> 6;            // wave 0..7
    const int wm   = w >> 2;              // 0..1 : 128-row band
    const int wn   = w & 3;               // 0..3 : 64-col band
    const int lr   = lane & 15;
    const int lk   = lane >> 4;

    const int phys  = blockIdx.x;
    const int xcd   = phys & 7;
    const int ord   = phys >> 3;          // 0..31
    const int chunk = xcd * 16 + (ord >> 1);   // 0..127
    const int ntile = ord & 1;
    const long k0   = (long)chunk * KC;

    // --- A staging (regs): thread t -> A row t>>1, k-half t&1 (16 floats).
    const int rowh = tid >> 1;
    const int h    = tid & 1;
    const int e    = rowh & 7;
    const float* qsrc = Q + (long)rowh * KTOT + k0 + h * 16;
    const int aw0 = rowh * 128 + (((2 * h + 0) ^ e) * 16);  // hi, k-local [0,8)
    const int aw1 = rowh * 128 + (((2 * h + 1) ^ e) * 16);  // hi, k-local [8,16)
    const int aw2 = rowh * 128 + (((2 * h + 4) ^ e) * 16);  // lo, k-local [0,8)
    const int aw3 = rowh * 128 + (((2 * h + 5) ^ e) * 16);  // lo, k-local [8,16)

    // --- B staging (DMA): 4 gld16/thread; slot s=i*512+tid -> row s>>3,
    // 16B-unit s&7; source chunk pre-swizzled c = u ^ (r&7); linear LDS dest.
    const float* gsrcB[4];
#pragma unroll
    for (int i = 0; i < 4; ++i) {
        int sIdx = i * 512 + tid;
        int r = sIdx >> 3, u = sIdx & 7;
        int c = u ^ (r & 7);
        gsrcB[i] = S + (long)(ntile * 256 + r) * KTOT + k0 + c * 4;
    }

    // --- frag read bases (row&7 == lr&7 since bands are multiples of 16)
    const int e2  = lr & 7;
    const int aHi = (wm * 128 + lr) * 128 + ((lk ^ e2) * 16);
    const int aLo = (wm * 128 + lr) * 128 + (((lk + 4) ^ e2) * 16);
    // B fp32: row rB, 8 floats at k lk*8..: 16B units lk*2, lk*2+1 (swizzled)
    int bO[4][2];
#pragma unroll
    for (int nj = 0; nj < 4; ++nj) {
        int rB = wn * 64 + nj * 16 + lr;
#pragma unroll
        for (int t = 0; t < 2; ++t)
            bO[nj][t] = BBASE + rB * 128 + (((lk * 2 + t) ^ e2) * 16);
    }

    f32x4 acc[8][4];
#pragma unroll
    for (int i = 0; i < 8; ++i)
#pragma unroll
        for (int j = 0; j < 4; ++j)
            acc[i][j] = (f32x4){0.f, 0.f, 0.f, 0.f};

    float ssq[4] = {0.f, 0.f, 0.f, 0.f};
    float4 pa0, pa1, pa2, pa3;

#define LOADREGS_A {                                                       \
    pa0 = *(const float4*)(qsrc);      pa1 = *(const float4*)(qsrc + 4);   \
    pa2 = *(const float4*)(qsrc + 8);  pa3 = *(const float4*)(qsrc + 12);  \
    qsrc += BK; }

#define SPLITSTORE_A(BASE) {                                               \
    uintx4 u0, u1, v0, v1;                                                 \
    split8u(pa0, pa1, u0, v0);                                             \
    split8u(pa2, pa3, u1, v1);                                             \
    *(uintx4*)&Lds[(BASE) + aw0] = u0;                                     \
    *(uintx4*)&Lds[(BASE) + aw1] = u1;                                     \
    *(uintx4*)&Lds[(BASE) + aw2] = v0;                                     \
    *(uintx4*)&Lds[(BASE) + aw3] = v1; }

#define STAGE_B(BASE) {                                                    \
    _Pragma("unroll")                                                      \
    for (int i = 0; i < 4; ++i) {                                          \
        gld16(gsrcB[i], &Lds[(BASE) + BBASE + (i * 512 + tid) * 16]);      \
        gsrcB[i] += BK;                                                    \
    } }

    // prologue: B(t0) DMA'd to buf0; A(t0) reg->split->buf0; A(t1) in regs.
    STAGE_B(0)
    LOADREGS_A
    SPLITSTORE_A(0)                    // compiler waits vmcnt for pa* use;
                                       // in-order: B-DMA (older) retired too
    LOADREGS_A                         // A(t1) in flight
    asm volatile("s_waitcnt lgkmcnt(0)" ::: "memory");
    __builtin_amdgcn_s_barrier();
    SB

    bf16x8 a0h, a0l, a1h, a1l, a2h, a2l;   // 3 rotating A pairs

    for (int s = 0; s < NSTEPS - 1; ++s) {
        const int cur = (s & 1) * BUFB;
        const int nxt = cur ^ BUFB;

        STAGE_B(nxt)                       // B(s+1) DMA (vmcnt, off lgkm path)
        SB
        // ramp: B(cur) fp32 reads + A0..A2 (2-deep from the start)
        float4 b00 = *(const float4*)&Lds[cur + bO[0][0]];
        float4 b01 = *(const float4*)&Lds[cur + bO[0][1]];
        float4 b10 = *(const float4*)&Lds[cur + bO[1][0]];
        float4 b11 = *(const float4*)&Lds[cur + bO[1][1]];
        float4 b20 = *(const float4*)&Lds[cur + bO[2][0]];
        float4 b21 = *(const float4*)&Lds[cur + bO[2][1]];
        float4 b30 = *(const float4*)&Lds[cur + bO[3][0]];
        float4 b31 = *(const float4*)&Lds[cur + bO[3][1]];
        SB
        a0h = LDF(cur + aHi);              a0l = LDF(cur + aLo);
        SB
        a1h = LDF(cur + aHi + 2048);       a1l = LDF(cur + aLo + 2048);
        SB
        a2h = LDF(cur + aHi + 4096);       a2l = LDF(cur + aLo + 4096);
        SB
        WAITL(6)                           // B8 done; A0,A1,A2 outstanding
        SB
        bf16x8 bh0, bl0, bh1, bl1, bh2, bl2, bh3, bl3;
        split8v(b00, b01, bh0, bl0);
        split8v(b10, b11, bh1, bl1);
        split8v(b20, b21, bh2, bl2);
        split8v(b30, b31, bh3, bl3);
        ssq[0] += b00.x*b00.x + b00.y*b00.y + b00.z*b00.z + b00.w*b00.w
                + b01.x*b01.x + b01.y*b01.y + b01.z*b01.z + b01.w*b01.w;
        ssq[1] += b10.x*b10.x + b10.y*b10.y + b10.z*b10.z + b10.w*b10.w
                + b11.x*b11.x + b11.y*b11.y + b11.z*b11.z + b11.w*b11.w;
        ssq[2] += b20.x*b20.x + b20.y*b20.y + b20.z*b20.z + b20.w*b20.w
                + b21.x*b21.x + b21.y*b21.y + b21.z*b21.z + b21.w*b21.w;
        ssq[3] += b30.x*b30.x + b30.y*b30.y + b30.z*b30.z + b30.w*b30.w
                + b31.x*b31.x + b31.y*b31.y + b31.z*b31.z + b31.w*b31.w;
        SB
        WAITL(4)                           // A0 done; A1,A2 outstanding
        SB
        MMB(0, a0h, a0l)
        SB
        SPLITSTORE_A(nxt)                  // consume pa* (A of s+1): W4
        SB
        a0h = LDF(cur + aHi + 6144);       a0l = LDF(cur + aLo + 6144);   // A3
        SB
        WAITL(8)                           // A1 done; [A2,W4,A3]
        SB
        MMB(1, a1h, a1l)
        SB
        if (s + 2 < NSTEPS) LOADREGS_A     // A(s+2) VMEM, overwrite safe now
        SB
        a1h = LDF(cur + aHi + 8192);       a1l = LDF(cur + aLo + 8192);   // A4
        SB
        WAITL(8)                           // A2 done; [W4,A3,A4]
        SB
        MMB(2, a2h, a2l)
        SB
        a2h = LDF(cur + aHi + 10240);      a2l = LDF(cur + aLo + 10240);  // A5
        SB
        WAITL(4)                           // W4+A3 done; [A4,A5]
        SB
        MMB(3, a0h, a0l)
        SB
        a0h = LDF(cur + aHi + 12288);      a0l = LDF(cur + aLo + 12288);  // A6
        SB
        WAITL(4)                           // A4 done; [A5,A6]
        SB
        MMB(4, a1h, a1l)
        SB
        a1h = LDF(cur + aHi + 14336);      a1l = LDF(cur + aLo + 14336);  // A7
        SB
        WAITL(4)                           // A5 done; [A6,A7]
        SB
        MMB(5, a2h, a2l)
        SB
        WAITL(2)                           // A6 done
        SB
        MMB(6, a0h, a0l)
        SB
        WAITL(0)                           // A7 done (all lgkm drained)
        SB
        MMB(7, a1h, a1l)
        SB
        if (s + 2 < NSTEPS) {
            asm volatile("s_waitcnt vmcnt(4)" ::: "memory");  // B-DMA done; A-loads fly
        } else {
            asm volatile("s_waitcnt vmcnt(0)" ::: "memory");  // no L_A issued: drain
        }
        SB
        __builtin_amdgcn_s_barrier();      // nxt (A writes + B DMA) visible
        SB
    }

    // peeled last step: pure consume, 2-deep ladder, clean counts
    {
        const int cur = ((NSTEPS - 1) & 1) * BUFB;
        float4 b00 = *(const float4*)&Lds[cur + bO[0][0]];
        float4 b01 = *(const float4*)&Lds[cur + bO[0][1]];
        float4 b10 = *(const float4*)&Lds[cur + bO[1][0]];
        float4 b11 = *(const float4*)&Lds[cur + bO[1][1]];
        float4 b20 = *(const float4*)&Lds[cur + bO[2][0]];
        float4 b21 = *(const float4*)&Lds[cur + bO[2][1]];
        float4 b30 = *(const float4*)&Lds[cur + bO[3][0]];
        float4 b31 = *(const float4*)&Lds[cur + bO[3][1]];
        SB
        a0h = LDF(cur + aHi);              a0l = LDF(cur + aLo);
        SB
        a1h = LDF(cur + aHi + 2048);       a1l = LDF(cur + aLo + 2048);
        SB
        a2h = LDF(cur + aHi + 4096);       a2l = LDF(cur + aLo + 4096);
        SB
        WAITL(6)
        SB
        bf16x8 bh0, bl0, bh1, bl1, bh2, bl2, bh3, bl3;
        split8v(b00, b01, bh0, bl0);
        split8v(b10, b11, bh1, bl1);
        split8v(b20, b21, bh2, bl2);
        split8v(b30, b31, bh3, bl3);
        ssq[0] += b00.x*b00.x + b00.y*b00.y + b00.z*b00.z + b00.w*b00.w
                + b01.x*b01.x + b01.y*b01.y + b01.z*b01.z + b01.w*b01.w;
        ssq[1] += b10.x*b10.x + b10.y*b10.y + b10.z*b10.z + b10.w*b10.w
                + b11.x*b11.x + b11.y*b11.y + b11.z*b11.z + b11.w*b11.w;
        ssq[2] += b20.x*b20.x + b20.y*b20.y + b20.z*b20.z + b20.w*b20.w
                + b21.x*b21.x + b21.y*b21.y + b21.z*b21.z + b21.w*b21.w;
        ssq[3] += b30.x*b30.x + b30.y*b30.y + b30.z*b30.z + b30.w*b30.w
                + b31.x*b31.x + b31.y*b31.y + b31.z*b31.z + b31.w*b31.w;
        SB
        WAITL(4)
        SB
        MMB(0, a0h, a0l)
        SB
        a0h = LDF(cur + aHi + 6144);       a0l = LDF(cur + aLo + 6144);
        SB
        WAITL(4)
        SB
        MMB(1, a1h, a1l)
        SB
        a1h = LDF(cur + aHi + 8192);       a1l = LDF(cur + aLo + 8192);
        SB
        WAITL(4)
        SB
        MMB(2, a2h, a2l)
        SB
        a2h = LDF(cur + aHi + 10240);      a2l = LDF(cur + aLo + 10240);
        SB
        WAITL(4)
        SB
        MMB(3, a0h, a0l)
        SB
        a0h = LDF(cur + aHi + 12288);      a0l = LDF(cur + aLo + 12288);
        SB
        WAITL(4)
        SB
        MMB(4, a1h, a1l)
        SB
        a1h = LDF(cur + aHi + 14336);      a1l = LDF(cur + aLo + 14336);
        SB
        WAITL(4)
        SB
        MMB(5, a2h, a2l)
        SB
        WAITL(2)
        SB
        MMB(6, a0h, a0l)
        SB
        WAITL(0)
        SB
        MMB(7, a1h, a1l)
        SB
    }
#undef LOADREGS_A
#undef SPLITSTORE_A
#undef STAGE_B

    // s2 partials: ssq[nj] covers B row wn*64+nj*16+lr, k-quarter lk (dup'd
    // across wm). Reduce lk groups; write from wm==0, lk==0.
#pragma unroll
    for (int nj = 0; nj < 4; ++nj) {
        float v = ssq[nj];
        v += __shfl_xor(v, 16);
        v += __shfl_xor(v, 32);
        if (wm == 0 && lk == 0)
            s2part[chunk * NS + ntile * 256 + wn * 64 + nj * 16 + lr] = v;
    }

    // write q.s partial tile  (C/D layout: col=lane&15, row=(lane>>4)*4+reg)
    float* op = Ppart + (long)chunk * (MQ * NS);
#pragma unroll
    for (int mi = 0; mi < 8; ++mi)
#pragma unroll
        for (int nj = 0; nj < 4; ++nj) {
            int mb = wm * 128 + mi * 16 + lk * 4;
            int nn = ntile * 256 + wn * 64 + nj * 16 + lr;
#pragma unroll
            for (int r = 0; r < 4; ++r)
                op[(long)(mb + r) * NS + nn] = acc[mi][nj][r];
        }
}

// ---------------------------------------------------------------------------
// K2: one block per query row: reduce K-split partials -> d2 row -> top-10
// ---------------------------------------------------------------------------
__global__ __launch_bounds__(256)
void k2_topk(const float* __restrict__ Ppart, const float* __restrict__ s2part,
             int* __restrict__ idxb)
{
    __shared__ float d2s[NS];
    const int m = blockIdx.x;
    const int tid = threadIdx.x;
    for (int nn = tid; nn < NS; nn += 256) {
        float s2 = 0.f, p = 0.f;
        for (int c = 0; c < KSPLIT; ++c) {
            s2 += s2part[c * NS + nn];
            p  += Ppart[(long)c * (MQ * NS) + (long)m * NS + nn];
        }
        d2s[nn] = s2 - 2.f * p;
    }
    __syncthreads();
    if (tid < 64) {
        unsigned long long key[8];
#pragma unroll
        for (int j = 0; j < 8; ++j) {
            int n = tid * 8 + j;
            unsigned int u = __float_as_uint(d2s[n]);
            u = (u >> 31) ? ~u : (u | 0x80000000u);   // total order, ascending
            key[j] = ((unsigned long long)u << 32) | (unsigned int)n;
        }
        for (int it = 0; it < 10; ++it) {
            unsigned long long best = key[0];
#pragma unroll
            for (int j = 1; j < 8; ++j) best = key[j] < best ? key[j] : best;
            for (int d = 1; d < 64; d <<= 1) {
                unsigned long long o = __shfl_xor(best, d);
                best = o < best ? o : best;
            }
            if (tid == 0) idxb[m * 10 + it] = (int)(best & 0xFFFFFFFFu);
#pragma unroll
            for (int j = 0; j < 8; ++j) if (key[j] == best) key[j] = ~0ull;
        }
    }
}

// ---------------------------------------------------------------------------
// K3: losses / best_k / threshold / mask  (integer sums < 2^24 -> exact fp32)
// ---------------------------------------------------------------------------
__global__ __launch_bounds__(256)
void k3_thresh(const int* __restrict__ idxb, float* __restrict__ mask)
{
    __shared__ int colsum[10];
    __shared__ float thr;
    const int tid = threadIdx.x;
    if (tid < 10) {
        int s = 0;
        for (int m = 0; m < MQ; ++m) s += idxb[m * 10 + tid];
        colsum[tid] = s;
    }
    __syncthreads();
    if (tid == 0) {
        float pre = 0.f, best = 3.4e38f;
        for (int k = 1; k <= 10; ++k) {
            pre += (float)colsum[k - 1];
            float loss = pre / (256.0f * (float)k);
            if (loss < best) best = loss;   // first-min == argmin; threshold = losses[best_k]
        }
        thr = best;
    }
    __syncthreads();
    if (tid < MQ) mask[tid] = ((float)idxb[tid * 10] < thr) ? 1.0f : 0.0f;
}

// ---------------------------------------------------------------------------
// K4: out = q * mask[row]   (float4, 2^18 floats per row)
// ---------------------------------------------------------------------------
__global__ __launch_bounds__(256)
void k4_apply(const float* __restrict__ Q, const float* __restrict__ mask,
              float* __restrict__ out)
{
    long i = ((long)blockIdx.x * 256 + threadIdx.x) * 4;
    int row = (int)(i >> 18);
    float4 v = *(const float4*)(Q + i);
    float mm = mask[row];
    v.x *= mm; v.y *= mm; v.z *= mm; v.w *= mm;
    *(float4*)(out + i) = v;
}

extern "C" void kernel_launch(void* const* d_in, const int* in_sizes, int n_in,
                              void* d_out, int out_size, void* d_ws, size_t ws_size,
                              hipStream_t stream)
{
    const float* Q = (const float*)d_in[0];
    const float* S = (const float*)d_in[1];
    float* out = (float*)d_out;

    // scratch inside d_out (overwritten by k4 afterwards); only mask must
    // survive into k4, so it lives in d_ws.
    float* Ppart  = out;                                   // 128*256*512 f32 = 64 MiB
    float* s2part = out + (long)KSPLIT * MQ * NS;          // 128*512 f32
    int*   idxb   = (int*)(s2part + KSPLIT * NS);          // 256*10 int
    float* mask   = (float*)d_ws;                          // 256 f32

    hipLaunchKernelGGL(k1_gemm,  dim3(256),   dim3(512), 0, stream, Q, S, Ppart, s2part);
    hipLaunchKernelGGL(k2_topk,  dim3(MQ),    dim3(256), 0, stream, Ppart, s2part, idxb);
    hipLaunchKernelGGL(k3_thresh,dim3(1),     dim3(256), 0, stream, idxb, mask);
    hipLaunchKernelGGL(k4_apply, dim3(65536), dim3(256), 0, stream, Q, mask, out);
}

// Round 17
// 348.479 us; speedup vs baseline: 1.0521x; 1.0521x over previous
//
#include <hip/hip_runtime.h>
#include <cstdint>

// ---------------------------------------------------------------------------
// q[256][262144], s[512][262144] fp32.
// rank by d2 ~ s2[n] - 2*(q.s)[m][n]; per-row top-10 -> threshold -> row mask
// out = q * mask[row]
// K1: 256x256-tile split-K GEMM, ONE barrier/step, one-batch-lookahead LDS
//     pipeline (R15, empirical optimum): SPLITSTORE (consume pa*) after
//     MMB(0), LOADREGS (overwrite pa*) after MMB(1); setprio on MFMA batches;
//     peeled last step with clean wait counts.
// K2: reduce partials + per-row top-10; K3: threshold+mask; K4: masked copy
// ---------------------------------------------------------------------------

typedef __attribute__((ext_vector_type(8))) __bf16 bf16x8;
typedef __attribute__((ext_vector_type(4))) float f32x4;
typedef __attribute__((ext_vector_type(4))) unsigned int uintx4;

#define KTOT 262144
#define MQ 256
#define NS 512
#define KSPLIT 128
#define KC 2048                 // KTOT / KSPLIT
#define BK 32
#define NSTEPS 64               // KC / BK
#define BBASE 32768             // B region offset inside a buffer
#define BUFB 65536              // one buffer: A 32K + B 32K (bf16 hi+lo)

__device__ inline unsigned int cvtpk_bf16(float a, float b) {
    unsigned int r;
    asm("v_cvt_pk_bf16_f32 %0, %1, %2" : "=v"(r) : "v"(a), "v"(b));
    return r; // r[15:0]=bf16(a), r[31:16]=bf16(b)
}

__device__ inline void split2(float a, float b, unsigned int& h, unsigned int& l) {
    h = cvtpk_bf16(a, b);
    float ra = a - __uint_as_float(h << 16);          // exact (Sterbenz)
    float rb = b - __uint_as_float(h & 0xFFFF0000u);  // exact
    l = cvtpk_bf16(ra, rb);
}

__device__ inline void split8u(const float4& x, const float4& y, uintx4& h, uintx4& l) {
    unsigned int h0, h1, h2, h3, l0, l1, l2, l3;
    split2(x.x, x.y, h0, l0);
    split2(x.z, x.w, h1, l1);
    split2(y.x, y.y, h2, l2);
    split2(y.z, y.w, h3, l3);
    h = (uintx4){h0, h1, h2, h3};
    l = (uintx4){l0, l1, l2, l3};
}

#define LDF(OFF) (*(const bf16x8*)&Lds[(OFF)])
#define SB __builtin_amdgcn_sched_barrier(0);
#define WAITL(N) asm volatile("s_waitcnt lgkmcnt(" #N ")" ::: "memory");

// term-major: 4 independent accumulator chains, dependent pairs 4 apart
#define MMB(MI, AH, AL)                                                                     \
    __builtin_amdgcn_s_setprio(1);                                                          \
    acc[MI][0] = __builtin_amdgcn_mfma_f32_16x16x32_bf16(AH, bh0, acc[MI][0], 0, 0, 0);     \
    acc[MI][1] = __builtin_amdgcn_mfma_f32_16x16x32_bf16(AH, bh1, acc[MI][1], 0, 0, 0);     \
    acc[MI][2] = __builtin_amdgcn_mfma_f32_16x16x32_bf16(AH, bh2, acc[MI][2], 0, 0, 0);     \
    acc[MI][3] = __builtin_amdgcn_mfma_f32_16x16x32_bf16(AH, bh3, acc[MI][3], 0, 0, 0);     \
    acc[MI][0] = __builtin_amdgcn_mfma_f32_16x16x32_bf16(AH, bl0, acc[MI][0], 0, 0, 0);     \
    acc[MI][1] = __builtin_amdgcn_mfma_f32_16x16x32_bf16(AH, bl1, acc[MI][1], 0, 0, 0);     \
    acc[MI][2] = __builtin_amdgcn_mfma_f32_16x16x32_bf16(AH, bl2, acc[MI][2], 0, 0, 0);     \
    acc[MI][3] = __builtin_amdgcn_mfma_f32_16x16x32_bf16(AH, bl3, acc[MI][3], 0, 0, 0);     \
    acc[MI][0] = __builtin_amdgcn_mfma_f32_16x16x32_bf16(AL, bh0, acc[MI][0], 0, 0, 0);     \
    acc[MI][1] = __builtin_amdgcn_mfma_f32_16x16x32_bf16(AL, bh1, acc[MI][1], 0, 0, 0);     \
    acc[MI][2] = __builtin_amdgcn_mfma_f32_16x16x32_bf16(AL, bh2, acc[MI][2], 0, 0, 0);     \
    acc[MI][3] = __builtin_amdgcn_mfma_f32_16x16x32_bf16(AL, bh3, acc[MI][3], 0, 0, 0);     \
    __builtin_amdgcn_s_setprio(0);

// ---------------------------------------------------------------------------
// K1: grid = 256 = 128 chunks x 2 ntiles, XCD-swizzled (chunk's pair shares
// the Q k-slice via L2). block = 512 threads (8 waves, 2x4, wave 128x64).
// ---------------------------------------------------------------------------
__global__ __launch_bounds__(512, 2)
void k1_gemm(const float* __restrict__ Q, const float* __restrict__ S,
             float* __restrict__ Ppart, float* __restrict__ s2part)
{
    __shared__ __align__(16) unsigned char Lds[2 * BUFB];   // 128 KiB dbuf

    const int tid  = threadIdx.x;
    const int lane = tid & 63;
    const int w    = tid >> 6;            // wave 0..7
    const int wm   = w >> 2;              // 0..1 : 128-row band
    const int wn   = w & 3;               // 0..3 : 64-col band
    const int lr   = lane & 15;
    const int lk   = lane >> 4;

    const int phys  = blockIdx.x;
    const int xcd   = phys & 7;
    const int ord   = phys >> 3;          // 0..31
    const int chunk = xcd * 16 + (ord >> 1);   // 0..127
    const int ntile = ord & 1;
    const long k0   = (long)chunk * KC;

    // --- staging: thread t handles A row t>>1 and B row t>>1, k-half t&1.
    const int rowh = tid >> 1;
    const int h    = tid & 1;
    const int e    = rowh & 7;
    const float* qsrc = Q + (long)rowh * KTOT + k0 + h * 16;
    const float* ssrc = S + (long)(ntile * 256 + rowh) * KTOT + k0 + h * 16;
    // row layout: 8x16B slots; logical: hi k[8s..8s+8) at s=0..3, lo at 4+s;
    // phys slot = logical ^ (row&7).
    const int aw0 = rowh * 128 + (((2 * h + 0) ^ e) * 16);  // hi, k-local [0,8)
    const int aw1 = rowh * 128 + (((2 * h + 1) ^ e) * 16);  // hi, k-local [8,16)
    const int aw2 = rowh * 128 + (((2 * h + 4) ^ e) * 16);  // lo, k-local [0,8)
    const int aw3 = rowh * 128 + (((2 * h + 5) ^ e) * 16);  // lo, k-local [8,16)

    // --- frag read bases (row&7 == lr&7 since bands are multiples of 16)
    const int e2  = lr & 7;
    const int aHi = (wm * 128 + lr) * 128 + ((lk ^ e2) * 16);
    const int aLo = (wm * 128 + lr) * 128 + (((lk + 4) ^ e2) * 16);
    const int bHi = BBASE + (wn * 64 + lr) * 128 + ((lk ^ e2) * 16);
    const int bLo = BBASE + (wn * 64 + lr) * 128 + (((lk + 4) ^ e2) * 16);

    f32x4 acc[8][4];
#pragma unroll
    for (int i = 0; i < 8; ++i)
#pragma unroll
        for (int j = 0; j < 4; ++j)
            acc[i][j] = (f32x4){0.f, 0.f, 0.f, 0.f};

    float ssq = 0.f;
    float4 pa0, pa1, pa2, pa3, pb0, pb1, pb2, pb3;

#define LOADREGS {                                                         \
    pa0 = *(const float4*)(qsrc);      pa1 = *(const float4*)(qsrc + 4);   \
    pa2 = *(const float4*)(qsrc + 8);  pa3 = *(const float4*)(qsrc + 12);  \
    pb0 = *(const float4*)(ssrc);      pb1 = *(const float4*)(ssrc + 4);   \
    pb2 = *(const float4*)(ssrc + 8);  pb3 = *(const float4*)(ssrc + 12);  \
    qsrc += BK; ssrc += BK; }

#define SPLITSTORE(BASE) {                                                 \
    uintx4 u0, u1, u2, u3, v0, v1, v2, v3;                                 \
    split8u(pa0, pa1, u0, v0);                                             \
    split8u(pa2, pa3, u1, v1);                                             \
    split8u(pb0, pb1, u2, v2);                                             \
    split8u(pb2, pb3, u3, v3);                                             \
    ssq += pb0.x*pb0.x + pb0.y*pb0.y + pb0.z*pb0.z + pb0.w*pb0.w           \
         + pb1.x*pb1.x + pb1.y*pb1.y + pb1.z*pb1.z + pb1.w*pb1.w           \
         + pb2.x*pb2.x + pb2.y*pb2.y + pb2.z*pb2.z + pb2.w*pb2.w           \
         + pb3.x*pb3.x + pb3.y*pb3.y + pb3.z*pb3.z + pb3.w*pb3.w;          \
    *(uintx4*)&Lds[(BASE) + aw0] = u0;                                     \
    *(uintx4*)&Lds[(BASE) + aw1] = u1;                                     \
    *(uintx4*)&Lds[(BASE) + aw2] = v0;                                     \
    *(uintx4*)&Lds[(BASE) + aw3] = v1;                                     \
    *(uintx4*)&Lds[(BASE) + BBASE + aw0] = u2;                             \
    *(uintx4*)&Lds[(BASE) + BBASE + aw1] = u3;                             \
    *(uintx4*)&Lds[(BASE) + BBASE + aw2] = v2;                             \
    *(uintx4*)&Lds[(BASE) + BBASE + aw3] = v3; }

    // prologue: tile0 staged to buf0; tile1 in staging regs (in flight)
    LOADREGS
    SPLITSTORE(0)
    LOADREGS
    asm volatile("s_waitcnt lgkmcnt(0)" ::: "memory");
    __builtin_amdgcn_s_barrier();
    SB

    for (int s = 0; s < NSTEPS - 1; ++s) {
        const int cur = (s & 1) * BUFB;
        const int nxt = cur ^ BUFB;

        // ramp: ONLY the B burst + A0/A1 (writes & VMEM issue deferred)
        bf16x8 bh0 = LDF(cur + bHi);          bf16x8 bl0 = LDF(cur + bLo);
        bf16x8 bh1 = LDF(cur + bHi + 2048);   bf16x8 bl1 = LDF(cur + bLo + 2048);
        bf16x8 bh2 = LDF(cur + bHi + 4096);   bf16x8 bl2 = LDF(cur + bLo + 4096);
        bf16x8 bh3 = LDF(cur + bHi + 6144);   bf16x8 bl3 = LDF(cur + bLo + 6144);
        bf16x8 aCh = LDF(cur + aHi);          bf16x8 aCl = LDF(cur + aLo);
        SB
        bf16x8 aNh = LDF(cur + aHi + 2048);   bf16x8 aNl = LDF(cur + aLo + 2048);
        SB
        WAITL(2)                               // B+A0 done; A1 outstanding
        SB
        MMB(0, aCh, aCl)
        SB
        SPLITSTORE(nxt)                        // consume pa* (tile s+1) -> 6 writes
        aCh = LDF(cur + aHi + 4096);          aCl = LDF(cur + aLo + 4096);
        SB
        WAITL(8)                               // A1 done; W6+A2 outstanding
        SB
        MMB(1, aNh, aNl)
        SB
        if (s + 2 < NSTEPS) LOADREGS           // overwrite pa* (tile s+2): safe now
        SB
        aNh = LDF(cur + aHi + 6144);          aNl = LDF(cur + aLo + 6144);
        SB
        WAITL(4)                               // W6+A2 done; A3 outstanding
        SB
        MMB(2, aCh, aCl)
        SB
        aCh = LDF(cur + aHi + 8192);          aCl = LDF(cur + aLo + 8192);
        SB
        WAITL(2)                               // A3 done; A4 outstanding
        SB
        MMB(3, aNh, aNl)
        SB
        aNh = LDF(cur + aHi + 10240);         aNl = LDF(cur + aLo + 10240);
        SB
        WAITL(2)                               // A4 done
        SB
        MMB(4, aCh, aCl)
        SB
        aCh = LDF(cur + aHi + 12288);         aCl = LDF(cur + aLo + 12288);
        SB
        WAITL(2)                               // A5 done
        SB
        MMB(5, aNh, aNl)
        SB
        aNh = LDF(cur + aHi + 14336);         aNl = LDF(cur + aLo + 14336);
        SB
        WAITL(2)                               // A6 done
        SB
        MMB(6, aCh, aCl)
        SB
        WAITL(0)                               // A7 done (+ everything)
        SB
        MMB(7, aNh, aNl)
        SB
        __builtin_amdgcn_s_barrier();          // writes of nxt visible to all
        SB
    }

    // peeled last step (no staging writes, no global loads): clean counts
    {
        const int cur = ((NSTEPS - 1) & 1) * BUFB;
        bf16x8 bh0 = LDF(cur + bHi);          bf16x8 bl0 = LDF(cur + bLo);
        bf16x8 bh1 = LDF(cur + bHi + 2048);   bf16x8 bl1 = LDF(cur + bLo + 2048);
        bf16x8 bh2 = LDF(cur + bHi + 4096);   bf16x8 bl2 = LDF(cur + bLo + 4096);
        bf16x8 bh3 = LDF(cur + bHi + 6144);   bf16x8 bl3 = LDF(cur + bLo + 6144);
        bf16x8 aCh = LDF(cur + aHi);          bf16x8 aCl = LDF(cur + aLo);
        SB
        bf16x8 aNh = LDF(cur + aHi + 2048);   bf16x8 aNl = LDF(cur + aLo + 2048);
        SB
        WAITL(2)
        SB
        MMB(0, aCh, aCl)
        SB
        aCh = LDF(cur + aHi + 4096);          aCl = LDF(cur + aLo + 4096);
        SB
        WAITL(2)
        SB
        MMB(1, aNh, aNl)
        SB
        aNh = LDF(cur + aHi + 6144);          aNl = LDF(cur + aLo + 6144);
        SB
        WAITL(2)
        SB
        MMB(2, aCh, aCl)
        SB
        aCh = LDF(cur + aHi + 8192);          aCl = LDF(cur + aLo + 8192);
        SB
        WAITL(2)
        SB
        MMB(3, aNh, aNl)
        SB
        aNh = LDF(cur + aHi + 10240);         aNl = LDF(cur + aLo + 10240);
        SB
        WAITL(2)
        SB
        MMB(4, aCh, aCl)
        SB
        aCh = LDF(cur + aHi + 12288);         aCl = LDF(cur + aLo + 12288);
        SB
        WAITL(2)
        SB
        MMB(5, aNh, aNl)
        SB
        aNh = LDF(cur + aHi + 14336);         aNl = LDF(cur + aLo + 14336);
        SB
        WAITL(2)
        SB
        MMB(6, aCh, aCl)
        SB
        WAITL(0)
        SB
        MMB(7, aNh, aNl)
        SB
    }
#undef LOADREGS
#undef SPLITSTORE

    // s2 partials: thread's ssq covers B row rowh (k-half h) over full KC.
    float o = __shfl_xor(ssq, 1);
    if (h == 0)
        s2part[chunk * NS + ntile * 256 + rowh] = ssq + o;

    // write q.s partial tile  (C/D layout: col=lane&15, row=(lane>>4)*4+reg)
    float* op = Ppart + (long)chunk * (MQ * NS);
#pragma unroll
    for (int mi = 0; mi < 8; ++mi)
#pragma unroll
        for (int nj = 0; nj < 4; ++nj) {
            int mb = wm * 128 + mi * 16 + lk * 4;
            int nn = ntile * 256 + wn * 64 + nj * 16 + lr;
#pragma unroll
            for (int r = 0; r < 4; ++r)
                op[(long)(mb + r) * NS + nn] = acc[mi][nj][r];
        }
}

// ---------------------------------------------------------------------------
// K2: one block per query row: reduce K-split partials -> d2 row -> top-10
// ---------------------------------------------------------------------------
__global__ __launch_bounds__(256)
void k2_topk(const float* __restrict__ Ppart, const float* __restrict__ s2part,
             int* __restrict__ idxb)
{
    __shared__ float d2s[NS];
    const int m = blockIdx.x;
    const int tid = threadIdx.x;
    for (int nn = tid; nn < NS; nn += 256) {
        float s2 = 0.f, p = 0.f;
        for (int c = 0; c < KSPLIT; ++c) {
            s2 += s2part[c * NS + nn];
            p  += Ppart[(long)c * (MQ * NS) + (long)m * NS + nn];
        }
        d2s[nn] = s2 - 2.f * p;
    }
    __syncthreads();
    if (tid < 64) {
        unsigned long long key[8];
#pragma unroll
        for (int j = 0; j < 8; ++j) {
            int n = tid * 8 + j;
            unsigned int u = __float_as_uint(d2s[n]);
            u = (u >> 31) ? ~u : (u | 0x80000000u);   // total order, ascending
            key[j] = ((unsigned long long)u << 32) | (unsigned int)n;
        }
        for (int it = 0; it < 10; ++it) {
            unsigned long long best = key[0];
#pragma unroll
            for (int j = 1; j < 8; ++j) best = key[j] < best ? key[j] : best;
            for (int d = 1; d < 64; d <<= 1) {
                unsigned long long o = __shfl_xor(best, d);
                best = o < best ? o : best;
            }
            if (tid == 0) idxb[m * 10 + it] = (int)(best & 0xFFFFFFFFu);
#pragma unroll
            for (int j = 0; j < 8; ++j) if (key[j] == best) key[j] = ~0ull;
        }
    }
}

// ---------------------------------------------------------------------------
// K3: losses / best_k / threshold / mask  (integer sums < 2^24 -> exact fp32)
// ---------------------------------------------------------------------------
__global__ __launch_bounds__(256)
void k3_thresh(const int* __restrict__ idxb, float* __restrict__ mask)
{
    __shared__ int colsum[10];
    __shared__ float thr;
    const int tid = threadIdx.x;
    if (tid < 10) {
        int s = 0;
        for (int m = 0; m < MQ; ++m) s += idxb[m * 10 + tid];
        colsum[tid] = s;
    }
    __syncthreads();
    if (tid == 0) {
        float pre = 0.f, best = 3.4e38f;
        for (int k = 1; k <= 10; ++k) {
            pre += (float)colsum[k - 1];
            float loss = pre / (256.0f * (float)k);
            if (loss < best) best = loss;   // first-min == argmin; threshold = losses[best_k]
        }
        thr = best;
    }
    __syncthreads();
    if (tid < MQ) mask[tid] = ((float)idxb[tid * 10] < thr) ? 1.0f : 0.0f;
}

// ---------------------------------------------------------------------------
// K4: out = q * mask[row]   (float4, 2^18 floats per row)
// ---------------------------------------------------------------------------
__global__ __launch_bounds__(256)
void k4_apply(const float* __restrict__ Q, const float* __restrict__ mask,
              float* __restrict__ out)
{
    long i = ((long)blockIdx.x * 256 + threadIdx.x) * 4;
    int row = (int)(i >> 18);
    float4 v = *(const float4*)(Q + i);
    float mm = mask[row];
    v.x *= mm; v.y *= mm; v.z *= mm; v.w *= mm;
    *(float4*)(out + i) = v;
}

extern "C" void kernel_launch(void* const* d_in, const int* in_sizes, int n_in,
                              void* d_out, int out_size, void* d_ws, size_t ws_size,
                              hipStream_t stream)
{
    const float* Q = (const float*)d_in[0];
    const float* S = (const float*)d_in[1];
    float* out = (float*)d_out;

    // scratch inside d_out (overwritten by k4 afterwards); only mask must
    // survive into k4, so it lives in d_ws.
    float* Ppart  = out;                                   // 128*256*512 f32 = 64 MiB
    float* s2part = out + (long)KSPLIT * MQ * NS;          // 128*512 f32
    int*   idxb   = (int*)(s2part + KSPLIT * NS);          // 256*10 int
    float* mask   = (float*)d_ws;                          // 256 f32

    hipLaunchKernelGGL(k1_gemm,  dim3(256),   dim3(512), 0, stream, Q, S, Ppart, s2part);
    hipLaunchKernelGGL(k2_topk,  dim3(MQ),    dim3(256), 0, stream, Ppart, s2part, idxb);
    hipLaunchKernelGGL(k3_thresh,dim3(1),     dim3(256), 0, stream, idxb, mask);
    hipLaunchKernelGGL(k4_apply, dim3(65536), dim3(256), 0, stream, Q, mask, out);
}

// Round 19
// 326.426 us; speedup vs baseline: 1.1232x; 1.0676x over previous
//
#include <hip/hip_runtime.h>
#include <cstdint>

// ---------------------------------------------------------------------------
// q[256][262144], s[512][262144] fp32.
// rank by d2 ~ s2[n] - 2*(q.s)[m][n]; per-row top-10 -> threshold -> row mask
// out = q * mask[row]
// K1: 256x256-tile split-K GEMM, ONE barrier/step, one-batch-lookahead LDS
//     pipeline (R15, empirical optimum): SPLITSTORE (consume pa*) after
//     MMB(0), LOADREGS (overwrite pa*) after MMB(1); setprio on MFMA batches;
//     peeled last step with clean wait counts.
// K2: reduce partials + per-row top-10; K3: threshold+mask; K4: masked copy
// ---------------------------------------------------------------------------

typedef __attribute__((ext_vector_type(8))) __bf16 bf16x8;
typedef __attribute__((ext_vector_type(4))) float f32x4;
typedef __attribute__((ext_vector_type(4))) unsigned int uintx4;

#define KTOT 262144
#define MQ 256
#define NS 512
#define KSPLIT 128
#define KC 2048                 // KTOT / KSPLIT
#define BK 32
#define NSTEPS 64               // KC / BK
#define BBASE 32768             // B region offset inside a buffer
#define BUFB 65536              // one buffer: A 32K + B 32K (bf16 hi+lo)

__device__ inline unsigned int cvtpk_bf16(float a, float b) {
    unsigned int r;
    asm("v_cvt_pk_bf16_f32 %0, %1, %2" : "=v"(r) : "v"(a), "v"(b));
    return r; // r[15:0]=bf16(a), r[31:16]=bf16(b)
}

__device__ inline void split2(float a, float b, unsigned int& h, unsigned int& l) {
    h = cvtpk_bf16(a, b);
    float ra = a - __uint_as_float(h << 16);          // exact (Sterbenz)
    float rb = b - __uint_as_float(h & 0xFFFF0000u);  // exact
    l = cvtpk_bf16(ra, rb);
}

__device__ inline void split8u(const float4& x, const float4& y, uintx4& h, uintx4& l) {
    unsigned int h0, h1, h2, h3, l0, l1, l2, l3;
    split2(x.x, x.y, h0, l0);
    split2(x.z, x.w, h1, l1);
    split2(y.x, y.y, h2, l2);
    split2(y.z, y.w, h3, l3);
    h = (uintx4){h0, h1, h2, h3};
    l = (uintx4){l0, l1, l2, l3};
}

#define LDF(OFF) (*(const bf16x8*)&Lds[(OFF)])
#define SB __builtin_amdgcn_sched_barrier(0);
#define WAITL(N) asm volatile("s_waitcnt lgkmcnt(" #N ")" ::: "memory");

// term-major: 4 independent accumulator chains, dependent pairs 4 apart
#define MMB(MI, AH, AL)                                                                     \
    __builtin_amdgcn_s_setprio(1);                                                          \
    acc[MI][0] = __builtin_amdgcn_mfma_f32_16x16x32_bf16(AH, bh0, acc[MI][0], 0, 0, 0);     \
    acc[MI][1] = __builtin_amdgcn_mfma_f32_16x16x32_bf16(AH, bh1, acc[MI][1], 0, 0, 0);     \
    acc[MI][2] = __builtin_amdgcn_mfma_f32_16x16x32_bf16(AH, bh2, acc[MI][2], 0, 0, 0);     \
    acc[MI][3] = __builtin_amdgcn_mfma_f32_16x16x32_bf16(AH, bh3, acc[MI][3], 0, 0, 0);     \
    acc[MI][0] = __builtin_amdgcn_mfma_f32_16x16x32_bf16(AH, bl0, acc[MI][0], 0, 0, 0);     \
    acc[MI][1] = __builtin_amdgcn_mfma_f32_16x16x32_bf16(AH, bl1, acc[MI][1], 0, 0, 0);     \
    acc[MI][2] = __builtin_amdgcn_mfma_f32_16x16x32_bf16(AH, bl2, acc[MI][2], 0, 0, 0);     \
    acc[MI][3] = __builtin_amdgcn_mfma_f32_16x16x32_bf16(AH, bl3, acc[MI][3], 0, 0, 0);     \
    acc[MI][0] = __builtin_amdgcn_mfma_f32_16x16x32_bf16(AL, bh0, acc[MI][0], 0, 0, 0);     \
    acc[MI][1] = __builtin_amdgcn_mfma_f32_16x16x32_bf16(AL, bh1, acc[MI][1], 0, 0, 0);     \
    acc[MI][2] = __builtin_amdgcn_mfma_f32_16x16x32_bf16(AL, bh2, acc[MI][2], 0, 0, 0);     \
    acc[MI][3] = __builtin_amdgcn_mfma_f32_16x16x32_bf16(AL, bh3, acc[MI][3], 0, 0, 0);     \
    __builtin_amdgcn_s_setprio(0);

// ---------------------------------------------------------------------------
// K1: grid = 256 = 128 chunks x 2 ntiles, XCD-swizzled (chunk's pair shares
// the Q k-slice via L2). block = 512 threads (8 waves, 2x4, wave 128x64).
// ---------------------------------------------------------------------------
__global__ __launch_bounds__(512, 2)
void k1_gemm(const float* __restrict__ Q, const float* __restrict__ S,
             float* __restrict__ Ppart, float* __restrict__ s2part)
{
    __shared__ __align__(16) unsigned char Lds[2 * BUFB];   // 128 KiB dbuf

    const int tid  = threadIdx.x;
    const int lane = tid & 63;
    const int w    = tid >> 6;            // wave 0..7
    const int wm   = w >> 2;              // 0..1 : 128-row band
    const int wn   = w & 3;               // 0..3 : 64-col band
    const int lr   = lane & 15;
    const int lk   = lane >> 4;

    const int phys  = blockIdx.x;
    const int xcd   = phys & 7;
    const int ord   = phys >> 3;          // 0..31
    const int chunk = xcd * 16 + (ord >> 1);   // 0..127
    const int ntile = ord & 1;
    const long k0   = (long)chunk * KC;

    // --- staging: thread t handles A row t>>1 and B row t>>1, k-half t&1.
    const int rowh = tid >> 1;
    const int h    = tid & 1;
    const int e    = rowh & 7;
    const float* qsrc = Q + (long)rowh * KTOT + k0 + h * 16;
    const float* ssrc = S + (long)(ntile * 256 + rowh) * KTOT + k0 + h * 16;
    // row layout: 8x16B slots; logical: hi k[8s..8s+8) at s=0..3, lo at 4+s;
    // phys slot = logical ^ (row&7).
    const int aw0 = rowh * 128 + (((2 * h + 0) ^ e) * 16);  // hi, k-local [0,8)
    const int aw1 = rowh * 128 + (((2 * h + 1) ^ e) * 16);  // hi, k-local [8,16)
    const int aw2 = rowh * 128 + (((2 * h + 4) ^ e) * 16);  // lo, k-local [0,8)
    const int aw3 = rowh * 128 + (((2 * h + 5) ^ e) * 16);  // lo, k-local [8,16)

    // --- frag read bases (row&7 == lr&7 since bands are multiples of 16)
    const int e2  = lr & 7;
    const int aHi = (wm * 128 + lr) * 128 + ((lk ^ e2) * 16);
    const int aLo = (wm * 128 + lr) * 128 + (((lk + 4) ^ e2) * 16);
    const int bHi = BBASE + (wn * 64 + lr) * 128 + ((lk ^ e2) * 16);
    const int bLo = BBASE + (wn * 64 + lr) * 128 + (((lk + 4) ^ e2) * 16);

    f32x4 acc[8][4];
#pragma unroll
    for (int i = 0; i < 8; ++i)
#pragma unroll
        for (int j = 0; j < 4; ++j)
            acc[i][j] = (f32x4){0.f, 0.f, 0.f, 0.f};

    float ssq = 0.f;
    float4 pa0, pa1, pa2, pa3, pb0, pb1, pb2, pb3;

#define LOADREGS {                                                         \
    pa0 = *(const float4*)(qsrc);      pa1 = *(const float4*)(qsrc + 4);   \
    pa2 = *(const float4*)(qsrc + 8);  pa3 = *(const float4*)(qsrc + 12);  \
    pb0 = *(const float4*)(ssrc);      pb1 = *(const float4*)(ssrc + 4);   \
    pb2 = *(const float4*)(ssrc + 8);  pb3 = *(const float4*)(ssrc + 12);  \
    qsrc += BK; ssrc += BK; }

#define SPLITSTORE(BASE) {                                                 \
    uintx4 u0, u1, u2, u3, v0, v1, v2, v3;                                 \
    split8u(pa0, pa1, u0, v0);                                             \
    split8u(pa2, pa3, u1, v1);                                             \
    split8u(pb0, pb1, u2, v2);                                             \
    split8u(pb2, pb3, u3, v3);                                             \
    ssq += pb0.x*pb0.x + pb0.y*pb0.y + pb0.z*pb0.z + pb0.w*pb0.w           \
         + pb1.x*pb1.x + pb1.y*pb1.y + pb1.z*pb1.z + pb1.w*pb1.w           \
         + pb2.x*pb2.x + pb2.y*pb2.y + pb2.z*pb2.z + pb2.w*pb2.w           \
         + pb3.x*pb3.x + pb3.y*pb3.y + pb3.z*pb3.z + pb3.w*pb3.w;          \
    *(uintx4*)&Lds[(BASE) + aw0] = u0;                                     \
    *(uintx4*)&Lds[(BASE) + aw1] = u1;                                     \
    *(uintx4*)&Lds[(BASE) + aw2] = v0;                                     \
    *(uintx4*)&Lds[(BASE) + aw3] = v1;                                     \
    *(uintx4*)&Lds[(BASE) + BBASE + aw0] = u2;                             \
    *(uintx4*)&Lds[(BASE) + BBASE + aw1] = u3;                             \
    *(uintx4*)&Lds[(BASE) + BBASE + aw2] = v2;                             \
    *(uintx4*)&Lds[(BASE) + BBASE + aw3] = v3; }

    // prologue: tile0 staged to buf0; tile1 in staging regs (in flight)
    LOADREGS
    SPLITSTORE(0)
    LOADREGS
    asm volatile("s_waitcnt lgkmcnt(0)" ::: "memory");
    __builtin_amdgcn_s_barrier();
    SB

    for (int s = 0; s < NSTEPS - 1; ++s) {
        const int cur = (s & 1) * BUFB;
        const int nxt = cur ^ BUFB;

        // ramp: ONLY the B burst + A0/A1 (writes & VMEM issue deferred)
        bf16x8 bh0 = LDF(cur + bHi);          bf16x8 bl0 = LDF(cur + bLo);
        bf16x8 bh1 = LDF(cur + bHi + 2048);   bf16x8 bl1 = LDF(cur + bLo + 2048);
        bf16x8 bh2 = LDF(cur + bHi + 4096);   bf16x8 bl2 = LDF(cur + bLo + 4096);
        bf16x8 bh3 = LDF(cur + bHi + 6144);   bf16x8 bl3 = LDF(cur + bLo + 6144);
        bf16x8 aCh = LDF(cur + aHi);          bf16x8 aCl = LDF(cur + aLo);
        SB
        bf16x8 aNh = LDF(cur + aHi + 2048);   bf16x8 aNl = LDF(cur + aLo + 2048);
        SB
        WAITL(2)                               // B+A0 done; A1 outstanding
        SB
        MMB(0, aCh, aCl)
        SB
        SPLITSTORE(nxt)                        // consume pa* (tile s+1) -> 6 writes
        aCh = LDF(cur + aHi + 4096);          aCl = LDF(cur + aLo + 4096);
        SB
        WAITL(8)                               // A1 done; W6+A2 outstanding
        SB
        MMB(1, aNh, aNl)
        SB
        if (s + 2 < NSTEPS) LOADREGS           // overwrite pa* (tile s+2): safe now
        SB
        aNh = LDF(cur + aHi + 6144);          aNl = LDF(cur + aLo + 6144);
        SB
        WAITL(4)                               // W6+A2 done; A3 outstanding
        SB
        MMB(2, aCh, aCl)
        SB
        aCh = LDF(cur + aHi + 8192);          aCl = LDF(cur + aLo + 8192);
        SB
        WAITL(2)                               // A3 done; A4 outstanding
        SB
        MMB(3, aNh, aNl)
        SB
        aNh = LDF(cur + aHi + 10240);         aNl = LDF(cur + aLo + 10240);
        SB
        WAITL(2)                               // A4 done
        SB
        MMB(4, aCh, aCl)
        SB
        aCh = LDF(cur + aHi + 12288);         aCl = LDF(cur + aLo + 12288);
        SB
        WAITL(2)                               // A5 done
        SB
        MMB(5, aNh, aNl)
        SB
        aNh = LDF(cur + aHi + 14336);         aNl = LDF(cur + aLo + 14336);
        SB
        WAITL(2)                               // A6 done
        SB
        MMB(6, aCh, aCl)
        SB
        WAITL(0)                               // A7 done (+ everything)
        SB
        MMB(7, aNh, aNl)
        SB
        __builtin_amdgcn_s_barrier();          // writes of nxt visible to all
        SB
    }

    // peeled last step (no staging writes, no global loads): clean counts
    {
        const int cur = ((NSTEPS - 1) & 1) * BUFB;
        bf16x8 bh0 = LDF(cur + bHi);          bf16x8 bl0 = LDF(cur + bLo);
        bf16x8 bh1 = LDF(cur + bHi + 2048);   bf16x8 bl1 = LDF(cur + bLo + 2048);
        bf16x8 bh2 = LDF(cur + bHi + 4096);   bf16x8 bl2 = LDF(cur + bLo + 4096);
        bf16x8 bh3 = LDF(cur + bHi + 6144);   bf16x8 bl3 = LDF(cur + bLo + 6144);
        bf16x8 aCh = LDF(cur + aHi);          bf16x8 aCl = LDF(cur + aLo);
        SB
        bf16x8 aNh = LDF(cur + aHi + 2048);   bf16x8 aNl = LDF(cur + aLo + 2048);
        SB
        WAITL(2)
        SB
        MMB(0, aCh, aCl)
        SB
        aCh = LDF(cur + aHi + 4096);          aCl = LDF(cur + aLo + 4096);
        SB
        WAITL(2)
        SB
        MMB(1, aNh, aNl)
        SB
        aNh = LDF(cur + aHi + 6144);          aNl = LDF(cur + aLo + 6144);
        SB
        WAITL(2)
        SB
        MMB(2, aCh, aCl)
        SB
        aCh = LDF(cur + aHi + 8192);          aCl = LDF(cur + aLo + 8192);
        SB
        WAITL(2)
        SB
        MMB(3, aNh, aNl)
        SB
        aNh = LDF(cur + aHi + 10240);         aNl = LDF(cur + aLo + 10240);
        SB
        WAITL(2)
        SB
        MMB(4, aCh, aCl)
        SB
        aCh = LDF(cur + aHi + 12288);         aCl = LDF(cur + aLo + 12288);
        SB
        WAITL(2)
        SB
        MMB(5, aNh, aNl)
        SB
        aNh = LDF(cur + aHi + 14336);         aNl = LDF(cur + aLo + 14336);
        SB
        WAITL(2)
        SB
        MMB(6, aCh, aCl)
        SB
        WAITL(0)
        SB
        MMB(7, aNh, aNl)
        SB
    }
#undef LOADREGS
#undef SPLITSTORE

    // s2 partials: thread's ssq covers B row rowh (k-half h) over full KC.
    float o = __shfl_xor(ssq, 1);
    if (h == 0)
        s2part[chunk * NS + ntile * 256 + rowh] = ssq + o;

    // write q.s partial tile  (C/D layout: col=lane&15, row=(lane>>4)*4+reg)
    float* op = Ppart + (long)chunk * (MQ * NS);
#pragma unroll
    for (int mi = 0; mi < 8; ++mi)
#pragma unroll
        for (int nj = 0; nj < 4; ++nj) {
            int mb = wm * 128 + mi * 16 + lk * 4;
            int nn = ntile * 256 + wn * 64 + nj * 16 + lr;
#pragma unroll
            for (int r = 0; r < 4; ++r)
                op[(long)(mb + r) * NS + nn] = acc[mi][nj][r];
        }
}

// ---------------------------------------------------------------------------
// K2: one block per query row: reduce K-split partials -> d2 row -> top-10
// ---------------------------------------------------------------------------
__global__ __launch_bounds__(256)
void k2_topk(const float* __restrict__ Ppart, const float* __restrict__ s2part,
             int* __restrict__ idxb)
{
    __shared__ float d2s[NS];
    const int m = blockIdx.x;
    const int tid = threadIdx.x;
    for (int nn = tid; nn < NS; nn += 256) {
        float s2 = 0.f, p = 0.f;
        for (int c = 0; c < KSPLIT; ++c) {
            s2 += s2part[c * NS + nn];
            p  += Ppart[(long)c * (MQ * NS) + (long)m * NS + nn];
        }
        d2s[nn] = s2 - 2.f * p;
    }
    __syncthreads();
    if (tid < 64) {
        unsigned long long key[8];
#pragma unroll
        for (int j = 0; j < 8; ++j) {
            int n = tid * 8 + j;
            unsigned int u = __float_as_uint(d2s[n]);
            u = (u >> 31) ? ~u : (u | 0x80000000u);   // total order, ascending
            key[j] = ((unsigned long long)u << 32) | (unsigned int)n;
        }
        for (int it = 0; it < 10; ++it) {
            unsigned long long best = key[0];
#pragma unroll
            for (int j = 1; j < 8; ++j) best = key[j] < best ? key[j] : best;
            for (int d = 1; d < 64; d <<= 1) {
                unsigned long long o = __shfl_xor(best, d);
                best = o < best ? o : best;
            }
            if (tid == 0) idxb[m * 10 + it] = (int)(best & 0xFFFFFFFFu);
#pragma unroll
            for (int j = 0; j < 8; ++j) if (key[j] == best) key[j] = ~0ull;
        }
    }
}

// ---------------------------------------------------------------------------
// K3: losses / best_k / threshold / mask  (integer sums < 2^24 -> exact fp32)
// ---------------------------------------------------------------------------
__global__ __launch_bounds__(256)
void k3_thresh(const int* __restrict__ idxb, float* __restrict__ mask)
{
    __shared__ int colsum[10];
    __shared__ float thr;
    const int tid = threadIdx.x;
    if (tid < 10) {
        int s = 0;
        for (int m = 0; m < MQ; ++m) s += idxb[m * 10 + tid];
        colsum[tid] = s;
    }
    __syncthreads();
    if (tid == 0) {
        float pre = 0.f, best = 3.4e38f;
        for (int k = 1; k <= 10; ++k) {
            pre += (float)colsum[k - 1];
            float loss = pre / (256.0f * (float)k);
            if (loss < best) best = loss;   // first-min == argmin; threshold = losses[best_k]
        }
        thr = best;
    }
    __syncthreads();
    if (tid < MQ) mask[tid] = ((float)idxb[tid * 10] < thr) ? 1.0f : 0.0f;
}

// ---------------------------------------------------------------------------
// K4: out = q * mask[row]   (float4, 2^18 floats per row)
// ---------------------------------------------------------------------------
__global__ __launch_bounds__(256)
void k4_apply(const float* __restrict__ Q, const float* __restrict__ mask,
              float* __restrict__ out)
{
    long i = ((long)blockIdx.x * 256 + threadIdx.x) * 4;
    int row = (int)(i >> 18);
    float4 v = *(const float4*)(Q + i);
    float mm = mask[row];
    v.x *= mm; v.y *= mm; v.z *= mm; v.w *= mm;
    *(float4*)(out + i) = v;
}

extern "C" void kernel_launch(void* const* d_in, const int* in_sizes, int n_in,
                              void* d_out, int out_size, void* d_ws, size_t ws_size,
                              hipStream_t stream)
{
    const float* Q = (const float*)d_in[0];
    const float* S = (const float*)d_in[1];
    float* out = (float*)d_out;

    // scratch inside d_out (overwritten by k4 afterwards); only mask must
    // survive into k4, so it lives in d_ws.
    float* Ppart  = out;                                   // 128*256*512 f32 = 64 MiB
    float* s2part = out + (long)KSPLIT * MQ * NS;          // 128*512 f32
    int*   idxb   = (int*)(s2part + KSPLIT * NS);          // 256*10 int
    float* mask   = (float*)d_ws;                          // 256 f32

    hipLaunchKernelGGL(k1_gemm,  dim3(256),   dim3(512), 0, stream, Q, S, Ppart, s2part);
    hipLaunchKernelGGL(k2_topk,  dim3(MQ),    dim3(256), 0, stream, Ppart, s2part, idxb);
    hipLaunchKernelGGL(k3_thresh,dim3(1),     dim3(256), 0, stream, idxb, mask);
    hipLaunchKernelGGL(k4_apply, dim3(65536), dim3(256), 0, stream, Q, mask, out);
}